// Round 2
// baseline (22074.660 us; speedup 1.0000x reference)
//
#include <hip/hip_runtime.h>

#define B_SZ   256
#define T_SZ   128
#define IN_DIM 512
#define EMB    1024
#define HID    1024
#define G4     4096
#define NCLS   10

// ---------------------------------------------------------------------------
// GEMM: C[M,N] = (ADD_C?C:0) + A@B(^T) + (BIAS?bias[n]:0)
//  A row-major [M,*] with row stride lda.
//  B_NT=true : Bm is [N][K] row-major (C = A @ Bm^T)
//  B_NT=false: Bm is [K][N] row-major (C = A @ Bm)
//  AROW=true : A row remap for x's [B][T] layout: logical row r=(t*B_SZ+b)
//              reads physical row b*T_SZ + arow_t0 + t.
// Requires M%BM==0, N%BN==0, K%BK==0, K%4==0, N%4==0.
// ---------------------------------------------------------------------------
template<int BM,int BN,int BK,int TM,int TN,bool ADD_C,bool BIAS,bool B_NT,bool AROW>
__global__ __launch_bounds__((BM/TM)*(BN/TN))
void gemm(const float* __restrict__ A, const float* __restrict__ Bm,
          const float* __restrict__ bias, float* __restrict__ C,
          int M, int N, int K, int lda, int arow_t0) {
    constexpr int THREADS = (BM/TM)*(BN/TN);
    __shared__ float As[BK][BM+4];
    __shared__ float Bs[BK][BN+4];

    const int tid  = threadIdx.x;
    const int tcol = tid % (BN/TN);
    const int trow = tid / (BN/TN);
    const int bm   = blockIdx.y * BM;
    const int bn   = blockIdx.x * BN;

    float acc[TM][TN];
#pragma unroll
    for (int i = 0; i < TM; ++i)
#pragma unroll
        for (int j = 0; j < TN; ++j) acc[i][j] = 0.f;

    for (int k0 = 0; k0 < K; k0 += BK) {
#pragma unroll
        for (int r = 0; r < BM*BK/4; r += THREADS) {
            int i  = r + tid;
            int m  = i / (BK/4);
            int kk = (i % (BK/4)) * 4;
            int row = bm + m;
            if (AROW) row = (row & (B_SZ-1)) * T_SZ + arow_t0 + (row >> 8);
            const float4 v = *(const float4*)(&A[(size_t)row * lda + k0 + kk]);
            As[kk+0][m] = v.x; As[kk+1][m] = v.y; As[kk+2][m] = v.z; As[kk+3][m] = v.w;
        }
        if (B_NT) {
#pragma unroll
            for (int r = 0; r < BN*BK/4; r += THREADS) {
                int i  = r + tid;
                int n  = i / (BK/4);
                int kk = (i % (BK/4)) * 4;
                const float4 v = *(const float4*)(&Bm[(size_t)(bn + n) * K + k0 + kk]);
                Bs[kk+0][n] = v.x; Bs[kk+1][n] = v.y; Bs[kk+2][n] = v.z; Bs[kk+3][n] = v.w;
            }
        } else {
#pragma unroll
            for (int r = 0; r < BK*BN/4; r += THREADS) {
                int i  = r + tid;
                int kk = i / (BN/4);
                int n4 = (i % (BN/4)) * 4;
                const float4 v = *(const float4*)(&Bm[(size_t)(k0 + kk) * N + bn + n4]);
                *(float4*)(&Bs[kk][n4]) = v;   // (BN+4)%4==0 keeps rows 16B-aligned
            }
        }
        __syncthreads();
#pragma unroll
        for (int k = 0; k < BK; ++k) {
            float a[TM], b[TN];
#pragma unroll
            for (int i = 0; i < TM; ++i) a[i] = As[k][trow*TM + i];
#pragma unroll
            for (int j = 0; j < TN; ++j) b[j] = Bs[k][tcol*TN + j];
#pragma unroll
            for (int i = 0; i < TM; ++i)
#pragma unroll
                for (int j = 0; j < TN; ++j) acc[i][j] += a[i] * b[j];
        }
        __syncthreads();
    }

#pragma unroll
    for (int i = 0; i < TM; ++i) {
        int m = bm + trow*TM + i;
#pragma unroll
        for (int j = 0; j < TN; ++j) {
            int n = bn + tcol*TN + j;
            float v = acc[i][j];
            if (BIAS)  v += bias[n];
            if (ADD_C) v += C[(size_t)m * N + n];
            C[(size_t)m * N + n] = v;
        }
    }
}

// bcomb[n] = b_ih0[n] + b_hh0[n] + dot(W_ih0[n,:], b_enc)   (one wave per row)
__global__ void build_bcomb(const float* __restrict__ W_ih0, const float* __restrict__ b_enc,
                            const float* __restrict__ b_ih0, const float* __restrict__ b_hh0,
                            float* __restrict__ bcomb) {
    int row  = blockIdx.x * 4 + (threadIdx.x >> 6);
    int lane = threadIdx.x & 63;
    const float* w = W_ih0 + (size_t)row * EMB;
    float s = 0.f;
    for (int k = lane; k < EMB; k += 64) s += w[k] * b_enc[k];
#pragma unroll
    for (int o = 32; o > 0; o >>= 1) s += __shfl_down(s, o);
    if (lane == 0) bcomb[row] = s + b_ih0[row] + b_hh0[row];
}

__global__ void addv(const float* __restrict__ a, const float* __restrict__ b,
                     float* __restrict__ o, int n) {
    int i = blockIdx.x * blockDim.x + threadIdx.x;
    if (i < n) o[i] = a[i] + b[i];
}

// LSTM cell epilogue, gate order i,f,g,o; gates include all biases.
__global__ void lstm_cell(const float* __restrict__ gates,
                          float* __restrict__ h, float* __restrict__ c) {
    int idx = blockIdx.x * blockDim.x + threadIdx.x;   // 0 .. B*HID
    int b = idx >> 10;
    int j = idx & 1023;
    const float* g = gates + (size_t)b * G4;
    float ig = g[j];
    float fg = g[HID + j];
    float gg = g[2*HID + j];
    float og = g[3*HID + j];
    float i_ = 1.f / (1.f + expf(-ig));
    float f_ = 1.f / (1.f + expf(-fg));
    float g_ = tanhf(gg);
    float o_ = 1.f / (1.f + expf(-og));
    float cn = f_ * c[idx] + i_ * g_;
    c[idx] = cn;
    h[idx] = o_ * tanhf(cn);
}

__global__ void classifier(const float* __restrict__ h, const float* __restrict__ Wc,
                           const float* __restrict__ bc, float* __restrict__ y) {
    int m   = blockIdx.x;
    int tid = threadIdx.x;
    float part[NCLS];
#pragma unroll
    for (int n = 0; n < NCLS; ++n) part[n] = 0.f;
    for (int k = tid; k < HID; k += 256) {
        float hv = h[(size_t)m * HID + k];
#pragma unroll
        for (int n = 0; n < NCLS; ++n) part[n] += hv * Wc[(size_t)n * HID + k];
    }
    __shared__ float sm[256];
    for (int n = 0; n < NCLS; ++n) {
        sm[tid] = part[n];
        __syncthreads();
        for (int s = 128; s > 0; s >>= 1) {
            if (tid < s) sm[tid] += sm[tid + s];
            __syncthreads();
        }
        if (tid == 0) y[(size_t)m * NCLS + n] = sm[0] + bc[n];
        __syncthreads();
    }
}

extern "C" void kernel_launch(void* const* d_in, const int* in_sizes, int n_in,
                              void* d_out, int out_size, void* d_ws, size_t ws_size,
                              hipStream_t stream) {
    const float* x      = (const float*)d_in[0];
    const float* W_enc  = (const float*)d_in[1];
    const float* b_enc  = (const float*)d_in[2];
    const float* W_ih0  = (const float*)d_in[3];
    const float* W_hh0  = (const float*)d_in[4];
    const float* b_ih0  = (const float*)d_in[5];
    const float* b_hh0  = (const float*)d_in[6];
    const float* W_ih1  = (const float*)d_in[7];
    const float* W_hh1  = (const float*)d_in[8];
    const float* b_ih1  = (const float*)d_in[9];
    const float* b_hh1  = (const float*)d_in[10];
    const float* W_cls  = (const float*)d_in[11];
    const float* b_cls  = (const float*)d_in[12];
    float* out = (float*)d_out;

    float* ws = (float*)d_ws;
    size_t off = 0;
    float* Wcomb  = ws + off; off += (size_t)G4 * IN_DIM;       // 2M floats
    float* bcomb  = ws + off; off += G4;
    float* bsum1  = ws + off; off += G4;
    float* h0     = ws + off; off += (size_t)B_SZ * HID;        // h0,c0,h1,c1 contiguous
    float* c0     = ws + off; off += (size_t)B_SZ * HID;
    float* h1     = ws + off; off += (size_t)B_SZ * HID;
    float* c1     = ws + off; off += (size_t)B_SZ * HID;
    float* gates1 = ws + off; off += (size_t)B_SZ * G4;
    float* gx0    = ws + off;                                   // tc * B * G4

    size_t ws_floats = ws_size / 4;
    size_t remain = (ws_floats > off) ? (ws_floats - off) : 0;
    int tc_max = (int)(remain / ((size_t)B_SZ * G4));
    int tc = 1;
    const int cands[8] = {128, 64, 32, 16, 8, 4, 2, 1};
    for (int i = 0; i < 8; ++i) if (cands[i] <= tc_max) { tc = cands[i]; break; }

    // --- setup: Wcomb = W_ih0 @ W_enc  (NN), bcomb, bsum1, zero state ---
    gemm<128,128,16,8,8,false,false,false,false>
        <<<dim3(IN_DIM/128, G4/128), 256, 0, stream>>>(
            W_ih0, W_enc, nullptr, Wcomb, G4, IN_DIM, EMB, EMB, 0);
    build_bcomb<<<G4/4, 256, 0, stream>>>(W_ih0, b_enc, b_ih0, b_hh0, bcomb);
    addv<<<G4/256, 256, 0, stream>>>(b_ih1, b_hh1, bsum1, G4);
    hipMemsetAsync(h0, 0, (size_t)4 * B_SZ * HID * sizeof(float), stream);

    // --- time loop, layers interleaved ---
    for (int t0 = 0; t0 < T_SZ; t0 += tc) {
        // gx0[(t-t0)*B + b] = x[b, t] @ Wcomb^T + bcomb
        gemm<128,128,16,8,8,false,true,true,true>
            <<<dim3(G4/128, tc*B_SZ/128), 256, 0, stream>>>(
                x, Wcomb, bcomb, gx0, tc*B_SZ, G4, IN_DIM, IN_DIM, t0);

        for (int t = t0; t < t0 + tc; ++t) {
            float* gt = gx0 + (size_t)(t - t0) * B_SZ * G4;
            // layer 0: gates += h0 @ W_hh0^T
            gemm<64,64,16,4,4,true,false,true,false>
                <<<dim3(G4/64, B_SZ/64), 256, 0, stream>>>(
                    h0, W_hh0, nullptr, gt, B_SZ, G4, HID, HID, 0);
            lstm_cell<<<(B_SZ*HID)/256, 256, 0, stream>>>(gt, h0, c0);
            // layer 1: gates1 = h0 @ W_ih1^T + bsum1 ; gates1 += h1 @ W_hh1^T
            gemm<64,64,16,4,4,false,true,true,false>
                <<<dim3(G4/64, B_SZ/64), 256, 0, stream>>>(
                    h0, W_ih1, bsum1, gates1, B_SZ, G4, HID, HID, 0);
            gemm<64,64,16,4,4,true,false,true,false>
                <<<dim3(G4/64, B_SZ/64), 256, 0, stream>>>(
                    h1, W_hh1, nullptr, gates1, B_SZ, G4, HID, HID, 0);
            lstm_cell<<<(B_SZ*HID)/256, 256, 0, stream>>>(gates1, h1, c1);
        }
    }

    classifier<<<B_SZ, 256, 0, stream>>>(h1, W_cls, b_cls, out);
}

// Round 3
// 19976.337 us; speedup vs baseline: 1.1050x; 1.1050x over previous
//
#include <hip/hip_runtime.h>

#define B_SZ   256
#define T_SZ   128
#define IN_DIM 512
#define EMB    1024
#define HID    1024
#define G4     4096
#define NCLS   10

typedef __attribute__((ext_vector_type(8))) short short8v;
typedef __attribute__((ext_vector_type(4))) float floatx4;

__device__ inline unsigned short bf16hi(float f) {
    union { float f; unsigned u; } v; v.f = f;
    unsigned r = v.u + 0x7fff + ((v.u >> 16) & 1);   // RNE
    return (unsigned short)(r >> 16);
}
__device__ inline float bf2f(unsigned short b) {
    union { unsigned u; float f; } v; v.u = ((unsigned)b) << 16;
    return v.f;
}

// ---------------------------------------------------------------------------
// fp32 vector GEMM (setup only): C[M,N] = A[M,K] @ B[K,N]
// ---------------------------------------------------------------------------
template<int BM,int BN,int BK,int TM,int TN>
__global__ __launch_bounds__((BM/TM)*(BN/TN))
void gemm_f32_nn(const float* __restrict__ A, const float* __restrict__ Bm,
                 float* __restrict__ C, int M, int N, int K) {
    constexpr int THREADS = (BM/TM)*(BN/TN);
    __shared__ float As[BK][BM+4];
    __shared__ float Bs[BK][BN+4];
    const int tid  = threadIdx.x;
    const int tcol = tid % (BN/TN);
    const int trow = tid / (BN/TN);
    const int bm   = blockIdx.y * BM;
    const int bn   = blockIdx.x * BN;
    float acc[TM][TN];
#pragma unroll
    for (int i = 0; i < TM; ++i)
#pragma unroll
        for (int j = 0; j < TN; ++j) acc[i][j] = 0.f;
    for (int k0 = 0; k0 < K; k0 += BK) {
#pragma unroll
        for (int r = 0; r < BM*BK/4; r += THREADS) {
            int i  = r + tid;
            int m  = i / (BK/4);
            int kk = (i % (BK/4)) * 4;
            const float4 v = *(const float4*)(&A[(size_t)(bm+m)*K + k0 + kk]);
            As[kk+0][m]=v.x; As[kk+1][m]=v.y; As[kk+2][m]=v.z; As[kk+3][m]=v.w;
        }
#pragma unroll
        for (int r = 0; r < BK*BN/4; r += THREADS) {
            int i  = r + tid;
            int kk = i / (BN/4);
            int n4 = (i % (BN/4)) * 4;
            const float4 v = *(const float4*)(&Bm[(size_t)(k0+kk)*N + bn + n4]);
            *(float4*)(&Bs[kk][n4]) = v;
        }
        __syncthreads();
#pragma unroll
        for (int k = 0; k < BK; ++k) {
            float a[TM], b[TN];
#pragma unroll
            for (int i = 0; i < TM; ++i) a[i] = As[k][trow*TM+i];
#pragma unroll
            for (int j = 0; j < TN; ++j) b[j] = Bs[k][tcol*TN+j];
#pragma unroll
            for (int i = 0; i < TM; ++i)
#pragma unroll
                for (int j = 0; j < TN; ++j) acc[i][j] += a[i]*b[j];
        }
        __syncthreads();
    }
#pragma unroll
    for (int i = 0; i < TM; ++i)
#pragma unroll
        for (int j = 0; j < TN; ++j)
            C[(size_t)(bm+trow*TM+i)*N + bn + tcol*TN + j] = acc[i][j];
}

// ---------------------------------------------------------------------------
// Weight swizzle: fp32 W[N][K] -> frag-major hi/lo bf16.
// frag (cg=c+c_off, kf): dst[((cg*kf_cnt+kf)*2+p)*512 + l*8 + j]
//   = W[c*16 + (l&15)][kf*32 + (l>>4)*8 + j]   (p=0 hi, p=1 lo)
// One thread per (c, kf, lane).
// ---------------------------------------------------------------------------
__global__ void swz_w(const float* __restrict__ W, unsigned short* __restrict__ dst,
                      int K, int kf_cnt, int c_off) {
    int gid = blockIdx.x * blockDim.x + threadIdx.x;
    int l  = gid & 63;
    int kf = (gid >> 6) % kf_cnt;
    int c  = gid / (64 * kf_cnt);
    const float* src = W + (size_t)(c*16 + (l & 15)) * K + kf*32 + ((l >> 4) * 8);
    short8v vh, vl;
#pragma unroll
    for (int j = 0; j < 8; ++j) {
        float f = src[j];
        unsigned short h = bf16hi(f);
        vh[j] = (short)h;
        vl[j] = (short)bf16hi(f - bf2f(h));
    }
    size_t base = ((size_t)((c + c_off) * kf_cnt + kf) * 2) * 512 + (size_t)l * 8;
    *(short8v*)(dst + base)       = vh;
    *(short8v*)(dst + base + 512) = vl;
}

// ---------------------------------------------------------------------------
// Split-bf16 3-pass MFMA GEMM.  C[M, 4096] (+bias) (+=) A @ B^T conceptually.
// A: either hi/lo bf16 (Ah/Al, row stride lda, col offset chosen per half)
//    or fp32 (Af, converted during staging; optional AROW remap for x layout).
// B: pre-swizzled frag-major hi/lo (Bz), kf_cnt = K/32.
// Tile: 128 rows x 128 cols per block, 4 waves (wave = 64x64 quadrant).
// Dual-output: blocks with col0 >= split_nt write C2 (+bias2, no add,
// A col-offset +HID) — used to fuse layer0-hh and layer1-hh per step.
// ---------------------------------------------------------------------------
__global__ __launch_bounds__(256)
void gemm3p(const unsigned short* __restrict__ Ah, const unsigned short* __restrict__ Al,
            const float* __restrict__ Af, int lda, int arow_t0,
            const unsigned short* __restrict__ Bz, int kf_cnt,
            float* __restrict__ C, const float* __restrict__ bias, int add_c,
            float* __restrict__ C2, const float* __restrict__ bias2, int split_nt) {
    __shared__ unsigned short Asl[8][2][64][8];   // [mfrag][p][lane][8] = 16 KB

    const int tid = threadIdx.x;
    const int w   = tid >> 6;
    const int l   = tid & 63;
    const int col0 = blockIdx.x * 128;
    const int bm   = blockIdx.y * 128;

    float* Cb = C; const float* bb = bias; int addc = add_c;
    int a_coff = 0; int ccol0 = col0;
    if (col0 >= split_nt) { Cb = C2; bb = bias2; addc = 0; a_coff = HID; ccol0 = col0 - split_nt; }

    const int rowhalf = w & 1;
    const int colhalf = w >> 1;

    floatx4 acc[4][4];
#pragma unroll
    for (int m = 0; m < 4; ++m)
#pragma unroll
        for (int c = 0; c < 4; ++c) acc[m][c] = (floatx4){0.f,0.f,0.f,0.f};

    // staging map: thread -> (mfrag sm, lanes sl, sl+1)
    const int sm = tid >> 5;
    const int sl = (tid & 31) * 2;

    // B fragment base pointers (per wave: 4 col-frags)
    const int cg_base = (col0 >> 4) + colhalf * 4;
    const unsigned short* bp[4];
#pragma unroll
    for (int c = 0; c < 4; ++c)
        bp[c] = Bz + ((size_t)(cg_base + c) * kf_cnt) * 1024 + (size_t)l * 8;

    short8v b0[4][2], b1[4][2];

    auto loadB = [&](int kf, short8v (&dst)[4][2]) {
#pragma unroll
        for (int c = 0; c < 4; ++c) {
            const unsigned short* p = bp[c] + (size_t)kf * 1024;
            dst[c][0] = *(const short8v*)p;
            dst[c][1] = *(const short8v*)(p + 512);
        }
    };

    auto stageA = [&](int kf) {
#pragma unroll
        for (int q = 0; q < 2; ++q) {
            int ll  = sl + q;
            int row = bm + sm * 16 + (ll & 15);
            int k0  = kf * 32 + ((ll >> 4) * 8);
            if (Af) {
                const float* src;
                if (arow_t0 >= 0) {
                    int b  = row & (B_SZ - 1);
                    int tl = row >> 8;
                    src = Af + ((size_t)b * T_SZ + arow_t0 + tl) * lda + k0;
                } else {
                    src = Af + (size_t)row * lda + k0;
                }
                floatx4 v0 = *(const floatx4*)src;
                floatx4 v1 = *(const floatx4*)(src + 4);
                short8v vh, vl;
#pragma unroll
                for (int j = 0; j < 8; ++j) {
                    float f = (j < 4) ? v0[j] : v1[j-4];
                    unsigned short h = bf16hi(f);
                    vh[j] = (short)h;
                    vl[j] = (short)bf16hi(f - bf2f(h));
                }
                *(short8v*)&Asl[sm][0][ll][0] = vh;
                *(short8v*)&Asl[sm][1][ll][0] = vl;
            } else {
                size_t o = (size_t)row * lda + a_coff + k0;
                *(short8v*)&Asl[sm][0][ll][0] = *(const short8v*)(Ah + o);
                *(short8v*)&Asl[sm][1][ll][0] = *(const short8v*)(Al + o);
            }
        }
    };

    auto body = [&](int kf, short8v (&bc)[4][2], short8v (&bn)[4][2]) {
        stageA(kf);
        __syncthreads();
        if (kf + 1 < kf_cnt) loadB(kf + 1, bn);   // prefetch, completes at next barrier
        short8v ah[4], al[4];
#pragma unroll
        for (int m = 0; m < 4; ++m) {
            ah[m] = *(const short8v*)&Asl[rowhalf*4 + m][0][l][0];
            al[m] = *(const short8v*)&Asl[rowhalf*4 + m][1][l][0];
        }
#pragma unroll
        for (int m = 0; m < 4; ++m)
#pragma unroll
            for (int c = 0; c < 4; ++c) {
                acc[m][c] = __builtin_amdgcn_mfma_f32_16x16x32_bf16(ah[m], bc[c][0], acc[m][c], 0, 0, 0);
                acc[m][c] = __builtin_amdgcn_mfma_f32_16x16x32_bf16(ah[m], bc[c][1], acc[m][c], 0, 0, 0);
                acc[m][c] = __builtin_amdgcn_mfma_f32_16x16x32_bf16(al[m], bc[c][0], acc[m][c], 0, 0, 0);
            }
        __syncthreads();
    };

    loadB(0, b0);
    for (int kf = 0; kf < kf_cnt; kf += 2) {
        body(kf,     b0, b1);
        body(kf + 1, b1, b0);
    }

    // epilogue: C/D layout col=lane&15, row=(lane>>4)*4+j  [m91-verified]
    const int r0 = bm + rowhalf * 64;
#pragma unroll
    for (int m = 0; m < 4; ++m)
#pragma unroll
        for (int c = 0; c < 4; ++c) {
            int colb = ccol0 + colhalf*64 + c*16 + (l & 15);
            float bv = bb ? bb[colb] : 0.f;
#pragma unroll
            for (int j = 0; j < 4; ++j) {
                int row = r0 + m*16 + ((l >> 4) * 4) + j;
                size_t o = (size_t)row * G4 + colb;
                float v = acc[m][c][j] + bv;
                if (addc) v += Cb[o];
                Cb[o] = v;
            }
        }
}

// ---------------------------------------------------------------------------
// LSTM cell: gates[b][4H] fully pre-accumulated. Writes h as bf16 hi/lo into
// hcat layout (row stride 2048, col offset h_off), c in place, optional fp32 h.
// ---------------------------------------------------------------------------
__global__ void cell_k(const float* __restrict__ gates, float* __restrict__ c,
                       unsigned short* __restrict__ h_hi, unsigned short* __restrict__ h_lo,
                       int h_off, float* __restrict__ hf) {
    int idx = blockIdx.x * 256 + threadIdx.x;    // 0 .. B*HID
    int b = idx >> 10;
    int j = idx & 1023;
    const float* g = gates + (size_t)b * G4;
    float ig = g[j], fg = g[j+1024], gg = g[j+2048], og = g[j+3072];
    float i_ = 1.f / (1.f + expf(-ig));
    float f_ = 1.f / (1.f + expf(-fg));
    float g_ = tanhf(gg);
    float o_ = 1.f / (1.f + expf(-og));
    float cn = f_ * c[idx] + i_ * g_;
    c[idx] = cn;
    float h = o_ * tanhf(cn);
    unsigned short hi = bf16hi(h);
    size_t ho = (size_t)b * 2048 + h_off + j;
    h_hi[ho] = hi;
    h_lo[ho] = bf16hi(h - bf2f(hi));
    if (hf) hf[idx] = h;
}

// bcomb[n] = b_ih0[n] + b_hh0[n] + dot(W_ih0[n,:], b_enc)
__global__ void build_bcomb(const float* __restrict__ W_ih0, const float* __restrict__ b_enc,
                            const float* __restrict__ b_ih0, const float* __restrict__ b_hh0,
                            float* __restrict__ bcomb) {
    int row  = blockIdx.x * 4 + (threadIdx.x >> 6);
    int lane = threadIdx.x & 63;
    const float* w = W_ih0 + (size_t)row * EMB;
    float s = 0.f;
    for (int k = lane; k < EMB; k += 64) s += w[k] * b_enc[k];
#pragma unroll
    for (int o = 32; o > 0; o >>= 1) s += __shfl_down(s, o);
    if (lane == 0) bcomb[row] = s + b_ih0[row] + b_hh0[row];
}

__global__ void addv(const float* __restrict__ a, const float* __restrict__ b,
                     float* __restrict__ o, int n) {
    int i = blockIdx.x * blockDim.x + threadIdx.x;
    if (i < n) o[i] = a[i] + b[i];
}

__global__ void classifier(const float* __restrict__ h, const float* __restrict__ Wc,
                           const float* __restrict__ bc, float* __restrict__ y) {
    int m   = blockIdx.x;
    int tid = threadIdx.x;
    float part[NCLS];
#pragma unroll
    for (int n = 0; n < NCLS; ++n) part[n] = 0.f;
    for (int k = tid; k < HID; k += 256) {
        float hv = h[(size_t)m * HID + k];
#pragma unroll
        for (int n = 0; n < NCLS; ++n) part[n] += hv * Wc[(size_t)n * HID + k];
    }
    __shared__ float sm[256];
    for (int n = 0; n < NCLS; ++n) {
        sm[tid] = part[n];
        __syncthreads();
        for (int s = 128; s > 0; s >>= 1) {
            if (tid < s) sm[tid] += sm[tid + s];
            __syncthreads();
        }
        if (tid == 0) y[(size_t)m * NCLS + n] = sm[0] + bc[n];
        __syncthreads();
    }
}

extern "C" void kernel_launch(void* const* d_in, const int* in_sizes, int n_in,
                              void* d_out, int out_size, void* d_ws, size_t ws_size,
                              hipStream_t stream) {
    const float* x      = (const float*)d_in[0];
    const float* W_enc  = (const float*)d_in[1];
    const float* b_enc  = (const float*)d_in[2];
    const float* W_ih0  = (const float*)d_in[3];
    const float* W_hh0  = (const float*)d_in[4];
    const float* b_ih0  = (const float*)d_in[5];
    const float* b_hh0  = (const float*)d_in[6];
    const float* W_ih1  = (const float*)d_in[7];
    const float* W_hh1  = (const float*)d_in[8];
    const float* b_ih1  = (const float*)d_in[9];
    const float* b_hh1  = (const float*)d_in[10];
    const float* W_cls  = (const float*)d_in[11];
    const float* b_cls  = (const float*)d_in[12];
    float* out = (float*)d_out;

    float* ws = (float*)d_ws;
    size_t off = 0;
    float*          Wcomb  = ws + off;                  off += (size_t)G4 * IN_DIM;
    unsigned short* WcombZ = (unsigned short*)(ws+off); off += (size_t)G4 * IN_DIM * 2 / 2;
    unsigned short* WA_Z   = (unsigned short*)(ws+off); off += (size_t)8192 * HID * 2 / 2;
    unsigned short* WihZ1  = (unsigned short*)(ws+off); off += (size_t)G4 * HID * 2 / 2;
    float*          bcomb  = ws + off;                  off += G4;
    float*          bsum1  = ws + off;                  off += G4;
    unsigned short* h_hi   = (unsigned short*)(ws+off); off += (size_t)B_SZ * 2048 / 2;
    unsigned short* h_lo   = (unsigned short*)(ws+off); off += (size_t)B_SZ * 2048 / 2;
    float*          c0     = ws + off;                  off += (size_t)B_SZ * HID;
    float*          c1     = ws + off;                  off += (size_t)B_SZ * HID;
    float*          h1f    = ws + off;                  off += (size_t)B_SZ * HID;
    float*          gates1 = ws + off;                  off += (size_t)B_SZ * G4;
    float*          gx0    = ws + off;

    size_t ws_floats = ws_size / 4;
    size_t remain = (ws_floats > off) ? (ws_floats - off) : 0;
    int tc_max = (int)(remain / ((size_t)B_SZ * G4));
    int tc = 1;
    const int cands[6] = {32, 16, 8, 4, 2, 1};
    for (int i = 0; i < 6; ++i) if (cands[i] <= tc_max) { tc = cands[i]; break; }

    // --- setup ---
    // Wcomb = W_ih0 @ W_enc  (fp32, [4096][512])
    gemm_f32_nn<128,128,16,8,8><<<dim3(IN_DIM/128, G4/128), 256, 0, stream>>>(
        W_ih0, W_enc, Wcomb, G4, IN_DIM, EMB);
    build_bcomb<<<G4/4, 256, 0, stream>>>(W_ih0, b_enc, b_ih0, b_hh0, bcomb);
    addv<<<G4/256, 256, 0, stream>>>(b_ih1, b_hh1, bsum1, G4);
    // swizzle weights to frag-major hi/lo
    swz_w<<<(G4/16)*16*64/256, 256, 0, stream>>>(Wcomb, WcombZ, IN_DIM, 16, 0);
    swz_w<<<(G4/16)*32*64/256, 256, 0, stream>>>(W_hh0, WA_Z, HID, 32, 0);
    swz_w<<<(G4/16)*32*64/256, 256, 0, stream>>>(W_hh1, WA_Z, HID, 32, 256);
    swz_w<<<(G4/16)*32*64/256, 256, 0, stream>>>(W_ih1, WihZ1, HID, 32, 0);
    // zero h (hi+lo) and c0, c1 — contiguous 4 MB
    hipMemsetAsync(h_hi, 0, (size_t)4 * B_SZ * HID * sizeof(float)/1 * 0 + (size_t)(B_SZ*2048*2*2 + B_SZ*HID*4*2), stream);

    const int BIG = 1 << 30;

    // --- time loop ---
    for (int t0 = 0; t0 < T_SZ; t0 += tc) {
        // gx0[(t-t0)*B + b] = x[b,t] @ Wcomb^T + bcomb   (split-bf16 MFMA)
        gemm3p<<<dim3(32, tc*2), 256, 0, stream>>>(
            nullptr, nullptr, x, IN_DIM, t0, WcombZ, 16,
            gx0, bcomb, 0, nullptr, nullptr, BIG);

        for (int t = t0; t < t0 + tc; ++t) {
            float* gxt = gx0 + (size_t)(t - t0) * B_SZ * G4;
            // fused: gates0 += h0@W_hh0^T (cols<4096, ADD into gxt)
            //        gates1  = h1@W_hh1^T + bsum1 (cols>=4096)
            gemm3p<<<dim3(64, 2), 256, 0, stream>>>(
                h_hi, h_lo, nullptr, 2048, -1, WA_Z, 32,
                gxt, nullptr, 1, gates1, bsum1, G4);
            cell_k<<<(B_SZ*HID)/256, 256, 0, stream>>>(gxt, c0, h_hi, h_lo, 0, nullptr);
            // gates1 += h0(t) @ W_ih1^T
            gemm3p<<<dim3(32, 2), 256, 0, stream>>>(
                h_hi, h_lo, nullptr, 2048, -1, WihZ1, 32,
                gates1, nullptr, 1, nullptr, nullptr, BIG);
            cell_k<<<(B_SZ*HID)/256, 256, 0, stream>>>(gates1, c1, h_hi, h_lo, HID, h1f);
        }
    }

    classifier<<<B_SZ, 256, 0, stream>>>(h1f, W_cls, b_cls, out);
}

// Round 4
// 10944.109 us; speedup vs baseline: 2.0170x; 1.8253x over previous
//
#include <hip/hip_runtime.h>

#define B_SZ   256
#define T_SZ   128
#define IN_DIM 512
#define EMB    1024
#define HID    1024
#define G4     4096
#define NCLS   10
#define PSTR   2560   // A-plane row stride (shorts): [x 512 | h0 1024 | h1 1024]

typedef __attribute__((ext_vector_type(8))) short short8v;
typedef __attribute__((ext_vector_type(4))) float floatx4;

__device__ __forceinline__ unsigned short bf16hi(float f) {
    union { float f; unsigned u; } v; v.f = f;
    unsigned r = v.u + 0x7fff + ((v.u >> 16) & 1);   // RNE
    return (unsigned short)(r >> 16);
}
__device__ __forceinline__ float bf2f(unsigned short b) {
    union { unsigned u; float f; } v; v.u = ((unsigned)b) << 16;
    return v.f;
}

// ---------------------------------------------------------------------------
// fp32 vector GEMM (setup only): C[M,N] = A[M,K] @ B[K,N]
// ---------------------------------------------------------------------------
template<int BM,int BN,int BK,int TM,int TN>
__global__ __launch_bounds__((BM/TM)*(BN/TN))
void gemm_f32_nn(const float* __restrict__ A, const float* __restrict__ Bm,
                 float* __restrict__ C, int M, int N, int K) {
    constexpr int THREADS = (BM/TM)*(BN/TN);
    __shared__ float As[BK][BM+4];
    __shared__ float Bs[BK][BN+4];
    const int tid  = threadIdx.x;
    const int tcol = tid % (BN/TN);
    const int trow = tid / (BN/TN);
    const int bm   = blockIdx.y * BM;
    const int bn   = blockIdx.x * BN;
    float acc[TM][TN];
#pragma unroll
    for (int i = 0; i < TM; ++i)
#pragma unroll
        for (int j = 0; j < TN; ++j) acc[i][j] = 0.f;
    for (int k0 = 0; k0 < K; k0 += BK) {
#pragma unroll
        for (int r = 0; r < BM*BK/4; r += THREADS) {
            int i  = r + tid;
            int m  = i / (BK/4);
            int kk = (i % (BK/4)) * 4;
            const float4 v = *(const float4*)(&A[(size_t)(bm+m)*K + k0 + kk]);
            As[kk+0][m]=v.x; As[kk+1][m]=v.y; As[kk+2][m]=v.z; As[kk+3][m]=v.w;
        }
#pragma unroll
        for (int r = 0; r < BK*BN/4; r += THREADS) {
            int i  = r + tid;
            int kk = i / (BN/4);
            int n4 = (i % (BN/4)) * 4;
            const float4 v = *(const float4*)(&Bm[(size_t)(k0+kk)*N + bn + n4]);
            *(float4*)(&Bs[kk][n4]) = v;
        }
        __syncthreads();
#pragma unroll
        for (int k = 0; k < BK; ++k) {
            float a[TM], b[TN];
#pragma unroll
            for (int i = 0; i < TM; ++i) a[i] = As[k][trow*TM+i];
#pragma unroll
            for (int j = 0; j < TN; ++j) b[j] = Bs[k][tcol*TN+j];
#pragma unroll
            for (int i = 0; i < TM; ++i)
#pragma unroll
                for (int j = 0; j < TN; ++j) acc[i][j] += a[i]*b[j];
        }
        __syncthreads();
    }
#pragma unroll
    for (int i = 0; i < TM; ++i)
#pragma unroll
        for (int j = 0; j < TN; ++j)
            C[(size_t)(bm+trow*TM+i)*N + bn + tcol*TN + j] = acc[i][j];
}

// ---------------------------------------------------------------------------
// Weight swizzle to frag-major hi/lo, gate-interleaved columns.
// Output col n (0..4095): unit j=n>>2, gate q=n&3 -> source row q*1024 + j.
// K split: kf < kf0 from M0 (width K0), else from M1 (width K1).
// frag (cf, kf): dst[((cf*kfcnt+kf)*2+p)*512 + l*8 + j]
// ---------------------------------------------------------------------------
__global__ void swz2(const float* __restrict__ M0, int K0, int kf0,
                     const float* __restrict__ M1, int K1, int kfcnt,
                     unsigned short* __restrict__ dst) {
    int gid = blockIdx.x * 256 + threadIdx.x;
    int l   = gid & 63;
    int kf  = (gid >> 6) % kfcnt;
    int cf  = gid / (64 * kfcnt);
    int n   = cf*16 + (l & 15);
    int row = ((n & 3) << 10) + (n >> 2);
    const float* src; int kk = (l >> 4) * 8;
    if (kf < kf0) { src = M0 + (size_t)row * K0; kk += kf * 32; }
    else          { src = M1 + (size_t)row * K1; kk += (kf - kf0) * 32; }
    short8v vh, vl;
#pragma unroll
    for (int j = 0; j < 8; ++j) {
        float f = src[kk + j];
        unsigned short h = bf16hi(f);
        vh[j] = (short)h;
        vl[j] = (short)bf16hi(f - bf2f(h));
    }
    size_t base = ((size_t)(cf * kfcnt + kf) * 2) * 512 + (size_t)l * 8;
    *(short8v*)(dst + base)       = vh;
    *(short8v*)(dst + base + 512) = vl;
}

// bcombI[4j+q] = b_ih0 + b_hh0 + W_ih0[row,:] . b_enc   (row = q*1024+j)
__global__ void build_bcombI(const float* __restrict__ W_ih0, const float* __restrict__ b_enc,
                             const float* __restrict__ b_ih0, const float* __restrict__ b_hh0,
                             float* __restrict__ bcombI) {
    int row  = blockIdx.x * 4 + (threadIdx.x >> 6);
    int lane = threadIdx.x & 63;
    const float* w = W_ih0 + (size_t)row * EMB;
    float s = 0.f;
    for (int k = lane; k < EMB; k += 64) s += w[k] * b_enc[k];
#pragma unroll
    for (int o = 32; o > 0; o >>= 1) s += __shfl_down(s, o);
    if (lane == 0) {
        int n = ((row & 1023) << 2) | (row >> 10);
        bcombI[n] = s + b_ih0[row] + b_hh0[row];
    }
}

__global__ void addvI(const float* __restrict__ a, const float* __restrict__ b,
                      float* __restrict__ o) {
    int i = blockIdx.x * 256 + threadIdx.x;
    int n = ((i & 1023) << 2) | (i >> 10);
    o[n] = a[i] + b[i];
}

// ---------------------------------------------------------------------------
// Persistent LSTM kernel. 256 blocks x 256 threads, co-resident.
// Block (rg = bid>>7, cg = bid&127): 128-row x 64-col output tile.
//   cg < 64  : gates0(t) cols cg*64..,  A = plane cols 0..1535  (x_t | h0), 48 kf
//   cg >= 64 : gates1(t-1),             A = plane cols 512..2559 (h0 | h1), 64 kf
// Epilogue: LSTM cell on the block's 16 units x 128 rows; c in registers.
// One grid barrier per phase; planes parity-double-buffered.
// ---------------------------------------------------------------------------
__device__ __forceinline__ void gridbar(unsigned* bar, unsigned target, int tid) {
    __syncthreads();
    if (tid == 0) {
        __threadfence();
        atomicAdd(bar, 1u);
        while (__hip_atomic_load(bar, __ATOMIC_RELAXED, __HIP_MEMORY_SCOPE_AGENT) < target)
            __builtin_amdgcn_s_sleep(1);
        __threadfence();
    }
    __syncthreads();
}

__device__ __forceinline__ void a_load(const unsigned short* __restrict__ ph,
                                       const unsigned short* __restrict__ pl,
                                       int r0, int koff, int sm, int sl,
                                       short8v rh[2], short8v rl[2]) {
#pragma unroll
    for (int q = 0; q < 2; ++q) {
        int ll = sl + q;
        size_t o = (size_t)(r0 + sm*16 + (ll & 15)) * PSTR + koff + ((ll >> 4) * 8);
        rh[q] = *(const short8v*)(ph + o);
        rl[q] = *(const short8v*)(pl + o);
    }
}

__device__ __forceinline__ void a_write(unsigned short (*A)[2][64][8], int sm, int sl,
                                        short8v rh[2], short8v rl[2]) {
#pragma unroll
    for (int q = 0; q < 2; ++q) {
        int ll = sl + q;
        *(short8v*)&A[sm][0][ll][0] = rh[q];
        *(short8v*)&A[sm][1][ll][0] = rl[q];
    }
}

__device__ __forceinline__ void load_b(const unsigned short* bp0, const unsigned short* bp1, int kf,
                                       short8v& h0, short8v& l0, short8v& h1, short8v& l1) {
    const unsigned short* p0 = bp0 + (size_t)kf * 1024;
    const unsigned short* p1 = bp1 + (size_t)kf * 1024;
    h0 = *(const short8v*)p0; l0 = *(const short8v*)(p0 + 512);
    h1 = *(const short8v*)p1; l1 = *(const short8v*)(p1 + 512);
}

__device__ __forceinline__ void mfma24(unsigned short (*A)[2][64][8], int rowhalf, int l,
                                       short8v bh0, short8v bl0, short8v bh1, short8v bl1,
                                       floatx4 (&acc)[4][2]) {
    short8v ah[4], al[4];
#pragma unroll
    for (int m = 0; m < 4; ++m) {
        ah[m] = *(const short8v*)&A[rowhalf*4 + m][0][l][0];
        al[m] = *(const short8v*)&A[rowhalf*4 + m][1][l][0];
    }
#pragma unroll
    for (int m = 0; m < 4; ++m) {
        acc[m][0] = __builtin_amdgcn_mfma_f32_16x16x32_bf16(ah[m], bh0, acc[m][0], 0, 0, 0);
        acc[m][0] = __builtin_amdgcn_mfma_f32_16x16x32_bf16(ah[m], bl0, acc[m][0], 0, 0, 0);
        acc[m][0] = __builtin_amdgcn_mfma_f32_16x16x32_bf16(al[m], bh0, acc[m][0], 0, 0, 0);
        acc[m][1] = __builtin_amdgcn_mfma_f32_16x16x32_bf16(ah[m], bh1, acc[m][1], 0, 0, 0);
        acc[m][1] = __builtin_amdgcn_mfma_f32_16x16x32_bf16(ah[m], bl1, acc[m][1], 0, 0, 0);
        acc[m][1] = __builtin_amdgcn_mfma_f32_16x16x32_bf16(al[m], bh1, acc[m][1], 0, 0, 0);
    }
}

__device__ __forceinline__ void store_xz(unsigned short* ph, unsigned short* pl,
                                         int bid, int tid, float2 xv) {
    unsigned short h0 = bf16hi(xv.x), h1 = bf16hi(xv.y);
    ushort2 hh; hh.x = h0; hh.y = h1;
    ushort2 lv; lv.x = bf16hi(xv.x - bf2f(h0)); lv.y = bf16hi(xv.y - bf2f(h1));
    size_t o = (size_t)bid * PSTR + tid * 2;
    *(ushort2*)(ph + o) = hh;
    *(ushort2*)(pl + o) = lv;
}

__global__ __launch_bounds__(256)
void lstm_persist(const float* __restrict__ x,
                  const unsigned short* __restrict__ WLz,
                  const unsigned short* __restrict__ WRz,
                  const float* __restrict__ biasLI, const float* __restrict__ biasRI,
                  unsigned short* __restrict__ p0h, unsigned short* __restrict__ p0l,
                  unsigned short* __restrict__ p1h, unsigned short* __restrict__ p1l,
                  const float* __restrict__ Wcls, const float* __restrict__ bcls,
                  float* __restrict__ out, unsigned* __restrict__ bar) {
    __shared__ unsigned short AslBuf[2][8][2][64][8];   // 32 KB (double-buffered A tile)
    __shared__ float gtile[128][64];                    // 32 KB (gate tile / reduce scratch)

    const int tid = threadIdx.x, bid = blockIdx.x;
    const int w = tid >> 6, l = tid & 63;
    const int rowhalf = w & 1, colhalf = w >> 1;
    const int cg = bid & 127, rg = bid >> 7;
    const bool is_left = (cg < 64);
    const int r0 = rg * 128;
    const int cgl = is_left ? cg : cg - 64;
    const int kfcnt = is_left ? 48 : 64;
    const int acol0 = is_left ? 0 : 512;
    const int hcol0 = is_left ? 512 : 1536;
    const int j0 = cgl * 16;
    const unsigned short* Bz = is_left ? WLz : WRz;
    const float* biasI = is_left ? biasLI : biasRI;
    const int sm = tid >> 5, sl = (tid & 31) * 2;

    unsigned short* PH[2] = {p0h, p1h};
    unsigned short* PL[2] = {p0l, p1l};

    const int cf0 = cgl * 4 + colhalf * 2;
    const unsigned short* bp0 = Bz + ((size_t)cf0       * kfcnt) * 1024 + (size_t)l * 8;
    const unsigned short* bp1 = Bz + ((size_t)(cf0 + 1) * kfcnt) * 1024 + (size_t)l * 8;

    float biasv0, biasv1;
    { int cA = cgl*64 + colhalf*32 + (l & 15);
      biasv0 = biasI[cA]; biasv1 = biasI[cA + 16]; }

    float cst[8];
#pragma unroll
    for (int i = 0; i < 8; ++i) cst[i] = 0.f;

    unsigned target = 0;

    // prologue: stage x(0) into plane 0
    {
        float2 xv = *(const float2*)&x[((size_t)bid * T_SZ) * IN_DIM + tid * 2];
        store_xz(p0h, p0l, bid, tid, xv);
    }
    target += 256; gridbar(bar, target, tid);

    for (int t = 0; t <= T_SZ; ++t) {
        const int cur = t & 1, nxt = cur ^ 1;
        const bool conv = (t < T_SZ - 1);
        float2 xv;
        if (conv) xv = *(const float2*)&x[((size_t)bid * T_SZ + t + 1) * IN_DIM + tid * 2];

        const bool active = is_left ? (t < T_SZ) : (t >= 1);
        if (active) {
            const unsigned short* ph = PH[cur];
            const unsigned short* plo = PL[cur];

            floatx4 acc[4][2];
#pragma unroll
            for (int m = 0; m < 4; ++m)
#pragma unroll
                for (int c = 0; c < 2; ++c) acc[m][c] = (floatx4){0.f,0.f,0.f,0.f};

            short8v rh[2], rl[2];
            short8v bAh0,bAl0,bAh1,bAl1, bBh0,bBl0,bBh1,bBl1;

            a_load(ph, plo, r0, acol0, sm, sl, rh, rl);
            a_write(&AslBuf[0][0], sm, sl, rh, rl);
            load_b(bp0, bp1, 0, bAh0, bAl0, bAh1, bAl1);
            load_b(bp0, bp1, 1, bBh0, bBl0, bBh1, bBl1);
            __syncthreads();

            for (int kf2 = 0; kf2 < kfcnt; kf2 += 2) {
                // kf = kf2 (reads buf 0, writes buf 1)
                a_load(ph, plo, r0, acol0 + (kf2+1)*32, sm, sl, rh, rl);
                mfma24(&AslBuf[0][0], rowhalf, l, bAh0, bAl0, bAh1, bAl1, acc);
                if (kf2 + 2 < kfcnt) load_b(bp0, bp1, kf2+2, bAh0, bAl0, bAh1, bAl1);
                a_write(&AslBuf[1][0], sm, sl, rh, rl);
                __syncthreads();
                // kf = kf2+1 (reads buf 1, writes buf 0)
                if (kf2 + 2 < kfcnt) a_load(ph, plo, r0, acol0 + (kf2+2)*32, sm, sl, rh, rl);
                mfma24(&AslBuf[1][0], rowhalf, l, bBh0, bBl0, bBh1, bBl1, acc);
                if (kf2 + 3 < kfcnt) load_b(bp0, bp1, kf2+3, bBh0, bBl0, bBh1, bBl1);
                if (kf2 + 2 < kfcnt) { a_write(&AslBuf[0][0], sm, sl, rh, rl); }
                __syncthreads();
            }

            // write gates (+bias) to LDS tile
#pragma unroll
            for (int m = 0; m < 4; ++m)
#pragma unroll
                for (int c = 0; c < 2; ++c) {
                    int col = colhalf*32 + c*16 + (l & 15);
                    float bv = c ? biasv1 : biasv0;
#pragma unroll
                    for (int jj = 0; jj < 4; ++jj)
                        gtile[rowhalf*64 + m*16 + ((l >> 4)*4) + jj][col] = acc[m][c][jj] + bv;
                }
            __syncthreads();

            // LSTM cell on 16 units x 128 rows (8 cells/thread), c in regs
            {
                int u = tid & 15, rg8 = tid >> 4;
                unsigned short* nh = PH[nxt];
                unsigned short* nl = PL[nxt];
#pragma unroll
                for (int i = 0; i < 8; ++i) {
                    int r = rg8*8 + i;
                    float4 gq = *(const float4*)&gtile[r][4*u];
                    float ii = 1.f / (1.f + expf(-gq.x));
                    float ff = 1.f / (1.f + expf(-gq.y));
                    float gg = tanhf(gq.z);
                    float oo = 1.f / (1.f + expf(-gq.w));
                    float cn = ff * cst[i] + ii * gg;
                    cst[i] = cn;
                    float h = oo * tanhf(cn);
                    unsigned short hh = bf16hi(h);
                    size_t o = (size_t)(r0 + r) * PSTR + hcol0 + j0 + u;
                    nh[o] = hh;
                    nl[o] = bf16hi(h - bf2f(hh));
                }
            }
        }

        if (conv) store_xz(PH[nxt], PL[nxt], bid, tid, xv);
        target += 256; gridbar(bar, target, tid);
    }

    // classifier: block bid -> batch row bid; h1 = plane[(T+1)&1] cols 1536..2559
    {
        const unsigned short* hh = PH[(T_SZ + 1) & 1];
        const unsigned short* hl = PL[(T_SZ + 1) & 1];
        float part[NCLS];
#pragma unroll
        for (int n = 0; n < NCLS; ++n) part[n] = 0.f;
        for (int k = tid; k < HID; k += 256) {
            size_t o = (size_t)bid * PSTR + 1536 + k;
            float hv = bf2f(hh[o]) + bf2f(hl[o]);
#pragma unroll
            for (int n = 0; n < NCLS; ++n) part[n] += hv * Wcls[(size_t)n * HID + k];
        }
        float* red = (float*)gtile;
        for (int n = 0; n < NCLS; ++n) {
            red[tid] = part[n];
            __syncthreads();
            for (int s = 128; s > 0; s >>= 1) {
                if (tid < s) red[tid] += red[tid + s];
                __syncthreads();
            }
            if (tid == 0) out[(size_t)bid * NCLS + n] = red[0] + bcls[n];
            __syncthreads();
        }
    }
}

extern "C" void kernel_launch(void* const* d_in, const int* in_sizes, int n_in,
                              void* d_out, int out_size, void* d_ws, size_t ws_size,
                              hipStream_t stream) {
    const float* x      = (const float*)d_in[0];
    const float* W_enc  = (const float*)d_in[1];
    const float* b_enc  = (const float*)d_in[2];
    const float* W_ih0  = (const float*)d_in[3];
    const float* W_hh0  = (const float*)d_in[4];
    const float* b_ih0  = (const float*)d_in[5];
    const float* b_hh0  = (const float*)d_in[6];
    const float* W_ih1  = (const float*)d_in[7];
    const float* W_hh1  = (const float*)d_in[8];
    const float* b_ih1  = (const float*)d_in[9];
    const float* b_hh1  = (const float*)d_in[10];
    const float* W_cls  = (const float*)d_in[11];
    const float* b_cls  = (const float*)d_in[12];
    float* out = (float*)d_out;

    float* ws = (float*)d_ws;
    size_t off = 0;
    unsigned short* WLz    = (unsigned short*)(ws + off); off += (size_t)G4 * 1536 * 2 / 2;  // 6.29M fl
    unsigned short* WRz    = (unsigned short*)(ws + off); off += (size_t)G4 * 2048 * 2 / 2;  // 8.39M fl
    float*          Wcomb  = ws + off;                    off += (size_t)G4 * IN_DIM;
    float*          biasLI = ws + off;                    off += G4;
    float*          biasRI = ws + off;                    off += G4;
    unsigned short* planes = (unsigned short*)(ws + off); off += (size_t)4 * B_SZ * PSTR / 2;
    unsigned*       bar    = (unsigned*)(ws + off);       off += 64;

    unsigned short* p0h = planes;
    unsigned short* p0l = p0h + (size_t)B_SZ * PSTR;
    unsigned short* p1h = p0l + (size_t)B_SZ * PSTR;
    unsigned short* p1l = p1h + (size_t)B_SZ * PSTR;

    // --- setup ---
    // Wcomb[4096][512] = W_ih0 @ W_enc
    gemm_f32_nn<128,128,16,8,8><<<dim3(IN_DIM/128, G4/128), 256, 0, stream>>>(
        W_ih0, W_enc, Wcomb, G4, IN_DIM, EMB);
    build_bcombI<<<G4/4, 256, 0, stream>>>(W_ih0, b_enc, b_ih0, b_hh0, biasLI);
    addvI<<<G4/256, 256, 0, stream>>>(b_ih1, b_hh1, biasRI);
    // WLz: [Wcomb(16 kf) | W_hh0(32 kf)] ; WRz: [W_ih1(32 kf) | W_hh1(32 kf)]
    swz2<<<64*48, 256, 0, stream>>>(Wcomb, IN_DIM, 16, W_hh0, HID, 48, WLz);
    swz2<<<64*64, 256, 0, stream>>>(W_ih1, HID, 32, W_hh1, HID, 64, WRz);
    hipMemsetAsync(planes, 0, (size_t)4 * B_SZ * PSTR * 2, stream);
    hipMemsetAsync(bar, 0, sizeof(unsigned), stream);

    // --- the whole recurrence in one kernel ---
    lstm_persist<<<256, 256, 0, stream>>>(
        x, WLz, WRz, biasLI, biasRI,
        p0h, p0l, p1h, p1l, W_cls, b_cls, out, bar);
}